// Round 10
// baseline (224.410 us; speedup 1.0000x reference)
//
#include <hip/hip_runtime.h>

#define BB 4
#define NN 256
#define DD 256
#define HH 256
#define NEGV -1.0e9f

typedef _Float16 half8 __attribute__((ext_vector_type(8)));
typedef __fp16   fp16x2 __attribute__((ext_vector_type(2)));
typedef float floatx4 __attribute__((ext_vector_type(4)));

// ---------------- prep: Wc/Wd -> f16 fragment-contiguous; Xt = X^T; S/T -------
// Wst layout: [ks 0..15][hgrp 0..15][q 0..3][cc 0..15][e 0..7] halves.
// Fragment (ks,hgrp,q) holds B16[k=ks*32+q*8+e][h=hgrp*16+cc]; k=2*d+t
// (t=0: Wc[d][h], t=1: Wd[d][h]).
// Xt layout: [b][d][j] fp32 (A-gen loads are j-contiguous/coalesced).
__global__ __launch_bounds__(256) void prep_kernel(const float* __restrict__ X,
                                                   const float* __restrict__ W1,
                                                   float* __restrict__ S,
                                                   float* __restrict__ T,
                                                   _Float16* __restrict__ Wst,
                                                   float* __restrict__ Xt) {
  const int g = blockIdx.x;    // d = 0..255
  const int h = threadIdx.x;   // 0..255

  // (a) weight conversion for d = g
  {
    const float wcv = W1[(size_t)(2 * DD + g) * HH + h];
    const float wdv = W1[(size_t)(3 * DD + g) * HH + h];
    const int ks = g >> 4;
    const int dd = g & 15;
    const int q  = dd >> 2;
    const int e  = (dd & 3) * 2;
    const int hgrp = h >> 4;
    const int ccw  = h & 15;
    _Float16* p = Wst + ((size_t)((ks * 16 + hgrp) * 4 + q) * 16 + ccw) * 8 + e;
    p[0] = (_Float16)wcv;
    p[1] = (_Float16)wdv;
  }

  // (b) S/T for 4 rows + X transpose
  const int row0 = g * 4;
  __shared__ float xr[4][DD];
#pragma unroll
  for (int r = 0; r < 4; ++r) xr[r][h] = X[(size_t)(row0 + r) * DD + h];
  __syncthreads();

  {
    const int bb = row0 >> 8;
    const int j0 = row0 & 255;
    float* xt = Xt + (size_t)bb * DD * NN + (size_t)h * NN + j0;
    xt[0] = xr[0][h]; xt[1] = xr[1][h]; xt[2] = xr[2][h]; xt[3] = xr[3][h];
  }

  const float* __restrict__ Wa = W1;
  const float* __restrict__ Wb = W1 + (size_t)DD * HH;
  float sa0 = 0.f, sa1 = 0.f, sa2 = 0.f, sa3 = 0.f;
  float sb0 = 0.f, sb1 = 0.f, sb2 = 0.f, sb3 = 0.f;
  for (int d = 0; d < DD; ++d) {
    const float wa = Wa[(size_t)d * HH + h];
    const float wb = Wb[(size_t)d * HH + h];
    sa0 = fmaf(xr[0][d], wa, sa0);  sb0 = fmaf(xr[0][d], wb, sb0);
    sa1 = fmaf(xr[1][d], wa, sa1);  sb1 = fmaf(xr[1][d], wb, sb1);
    sa2 = fmaf(xr[2][d], wa, sa2);  sb2 = fmaf(xr[2][d], wb, sb2);
    sa3 = fmaf(xr[3][d], wa, sa3);  sb3 = fmaf(xr[3][d], wb, sb3);
  }
  S[(size_t)(row0 + 0) * HH + h] = sa0;  T[(size_t)(row0 + 0) * HH + h] = sb0;
  S[(size_t)(row0 + 1) * HH + h] = sa1;  T[(size_t)(row0 + 1) * HH + h] = sb1;
  S[(size_t)(row0 + 2) * HH + h] = sa2;  T[(size_t)(row0 + 2) * HH + h] = sb2;
  S[(size_t)(row0 + 3) * HH + h] = sa3;  T[(size_t)(row0 + 3) * HH + h] = sb3;
}

// A-fragment pack, no stack objects.
__device__ __forceinline__ half8 make_afrag(float ia, float ib, float ic, float id,
                                            float ja, float jb, float jc, float jd) {
  fp16x2 p0 = __builtin_amdgcn_cvt_pkrtz(__builtin_fabsf(ia - ja), ia * ja);
  fp16x2 p1 = __builtin_amdgcn_cvt_pkrtz(__builtin_fabsf(ib - jb), ib * jb);
  fp16x2 p2 = __builtin_amdgcn_cvt_pkrtz(__builtin_fabsf(ic - jc), ic * jc);
  fp16x2 p3 = __builtin_amdgcn_cvt_pkrtz(__builtin_fabsf(id - jd), id * jd);
  uint4 u;
  u.x = __builtin_bit_cast(unsigned int, p0);
  u.y = __builtin_bit_cast(unsigned int, p1);
  u.z = __builtin_bit_cast(unsigned int, p2);
  u.w = __builtin_bit_cast(unsigned int, p3);
  return __builtin_bit_cast(half8, u);
}

#define MFMA16(af, bf, acc) acc = __builtin_amdgcn_mfma_f32_16x16x32_f16(af, bf, acc, 0, 0, 0)

// ---------------- score: one block per (b,i) x 128-j half ----------------------
// 2048 blocks x 512 thr = 8 waves (wj = wid&1: 64 j, hg = wid>>1: 64 h).
// NEW vs R9: A-fragments are built ONCE per block into LDS (fragment-contiguous,
// same layout as B) by all 512 threads, then read with conflict-free b128 —
// eliminates the 4x-redundant per-wave A-gen that made R9 VALU-bound (51% VALU,
// 19% MFMA), and removes Xs (whose staging caused the residual 4.19M conflicts).
__global__ __launch_bounds__(512) void score_mfma(
    const float* __restrict__ X,  const float* __restrict__ b1,
    const float* __restrict__ W2, const float* __restrict__ b2,
    const float* __restrict__ S,  const float* __restrict__ T,
    const _Float16* __restrict__ Wst, const float* __restrict__ Xt,
    float* __restrict__ Sc) {

  const int blk   = blockIdx.x;
  const int bi    = blk >> 1;       // b*256 + i
  const int jbase = (blk & 1) * 128;
  const int b     = bi >> 8;
  const int i     = bi & 255;
  const int t     = threadIdx.x;
  const int lane  = t & 63;
  const int wid   = t >> 6;         // 0..7
  const int wj    = wid & 1;
  const int hg    = wid >> 1;       // 0..3
  const int q     = lane >> 4;
  const int cc    = lane & 15;

  __shared__ __align__(16) float    xi_s[DD];
  __shared__ float pre_s[HH];
  __shared__ float w2_s[HH];
  __shared__ __align__(16) _Float16 As[2][4096];   // A frags, 8 KB/buf
  __shared__ __align__(16) _Float16 Bs[2][8192];   // B frags, 16 KB/buf
  __shared__ float sc_s[4][128];

  if (t < 256) {
    xi_s[t]  = X[(size_t)bi * DD + t];
    pre_s[t] = S[(size_t)bi * HH + t] + b1[t];
    w2_s[t]  = W2[t];
  }
  __syncthreads();                    // xi_s needed by A-gen

  const float* __restrict__ Tb = T + (size_t)b * NN * HH;

  // A-gen role: thread t handles (qa = t>>7, jl = t&127): d = ks*16 + qa*4 + dd.
  const int qa = t >> 7;
  const int jl = t & 127;
  const float* __restrict__ xsrc = Xt + (size_t)b * DD * NN + jbase + jl;
  const int awo = ((jl >> 4) * 4 + qa) * 128 + (jl & 15) * 8;  // halves

  // B staging: thread t copies 32 contiguous bytes at byte t*32.
  const char* __restrict__ WstB = (const char*)Wst;   // kstep ks at byte ks*16384

  // fragment read offsets (halves): frag(tile,q) at (tile*4+q)*128 + cc*8
  const int bro = hg * 2048 + lane * 8;   // hh advances +512
  const int aro = wj * 2048 + lane * 8;   // jj advances +512

  floatx4 a00 = (floatx4)0.f, a01 = (floatx4)0.f, a02 = (floatx4)0.f, a03 = (floatx4)0.f;
  floatx4 a10 = (floatx4)0.f, a11 = (floatx4)0.f, a12 = (floatx4)0.f, a13 = (floatx4)0.f;
  floatx4 a20 = (floatx4)0.f, a21 = (floatx4)0.f, a22 = (floatx4)0.f, a23 = (floatx4)0.f;
  floatx4 a30 = (floatx4)0.f, a31 = (floatx4)0.f, a32 = (floatx4)0.f, a33 = (floatx4)0.f;

  // prologue: stage kstep 0 into buffer 0
  {
    const uint4 bv0 = *(const uint4*)(WstB + (size_t)t * 32);
    const uint4 bv1 = *(const uint4*)(WstB + (size_t)t * 32 + 16);
    const float xj0 = xsrc[(size_t)(qa * 4 + 0) * NN];
    const float xj1 = xsrc[(size_t)(qa * 4 + 1) * NN];
    const float xj2 = xsrc[(size_t)(qa * 4 + 2) * NN];
    const float xj3 = xsrc[(size_t)(qa * 4 + 3) * NN];
    *(uint4*)((char*)&Bs[0][0] + t * 32)      = bv0;
    *(uint4*)((char*)&Bs[0][0] + t * 32 + 16) = bv1;
    const half8 av = make_afrag(xi_s[qa * 4 + 0], xi_s[qa * 4 + 1],
                                xi_s[qa * 4 + 2], xi_s[qa * 4 + 3],
                                xj0, xj1, xj2, xj3);
    *(half8*)&As[0][awo] = av;
  }
  __syncthreads();

#pragma unroll 2
  for (int ks = 0; ks < 16; ++ks) {
    const int cur = ks & 1;
    uint4 nb0, nb1;
    float nx0, nx1, nx2, nx3;
    if (ks < 15) {
      nb0 = *(const uint4*)(WstB + (size_t)(ks + 1) * 16384 + (size_t)t * 32);
      nb1 = *(const uint4*)(WstB + (size_t)(ks + 1) * 16384 + (size_t)t * 32 + 16);
      const float* __restrict__ xs2 = xsrc + (size_t)((ks + 1) * 16 + qa * 4) * NN;
      nx0 = xs2[0]; nx1 = xs2[NN]; nx2 = xs2[2 * NN]; nx3 = xs2[3 * NN];
    }

    // ---- compute kstep ks from buffer cur ----
    {
      const _Float16* __restrict__ ap = &As[cur][0];
      const _Float16* __restrict__ bp = &Bs[cur][0];
      const half8 bf0 = *(const half8*)&bp[bro];
      const half8 bf1 = *(const half8*)&bp[bro + 512];
      const half8 bf2 = *(const half8*)&bp[bro + 1024];
      const half8 bf3 = *(const half8*)&bp[bro + 1536];
      {
        const half8 af = *(const half8*)&ap[aro];
        MFMA16(af, bf0, a00); MFMA16(af, bf1, a01); MFMA16(af, bf2, a02); MFMA16(af, bf3, a03);
      }
      {
        const half8 af = *(const half8*)&ap[aro + 512];
        MFMA16(af, bf0, a10); MFMA16(af, bf1, a11); MFMA16(af, bf2, a12); MFMA16(af, bf3, a13);
      }
      {
        const half8 af = *(const half8*)&ap[aro + 1024];
        MFMA16(af, bf0, a20); MFMA16(af, bf1, a21); MFMA16(af, bf2, a22); MFMA16(af, bf3, a23);
      }
      {
        const half8 af = *(const half8*)&ap[aro + 1536];
        MFMA16(af, bf0, a30); MFMA16(af, bf1, a31); MFMA16(af, bf2, a32); MFMA16(af, bf3, a33);
      }
    }

    if (ks < 15) {
      const int nxt = cur ^ 1;
      *(uint4*)((char*)&Bs[nxt][0] + t * 32)      = nb0;
      *(uint4*)((char*)&Bs[nxt][0] + t * 32 + 16) = nb1;
      const int d0 = (ks + 1) * 16 + qa * 4;
      const half8 av = make_afrag(xi_s[d0], xi_s[d0 + 1], xi_s[d0 + 2], xi_s[d0 + 3],
                                  nx0, nx1, nx2, nx3);
      *(half8*)&As[nxt][awo] = av;
    }
    __syncthreads();
  }

  // ---- epilogue: + S_i + T_j + b1, silu, dot w2 ----
  float p00 = 0.f, p01 = 0.f, p02 = 0.f, p03 = 0.f;
  float p10 = 0.f, p11 = 0.f, p12 = 0.f, p13 = 0.f;
  float p20 = 0.f, p21 = 0.f, p22 = 0.f, p23 = 0.f;
  float p30 = 0.f, p31 = 0.f, p32 = 0.f, p33 = 0.f;

#define EPI_ONE(A, jj, r, P) { \
    const float tv = Tb[(size_t)(jbase + wj * 64 + jj * 16 + q * 4 + r) * HH + h]; \
    const float hv = A[r] + pv + tv; \
    const float sv = hv * __frcp_rn(1.f + __expf(-hv)); \
    P = fmaf(sv, w2v, P); }

#define EPI_HH(hh, A0, A1, A2, A3) { \
    const int h = hg * 64 + hh * 16 + cc; \
    const float w2v = w2_s[h]; \
    const float pv  = pre_s[h]; \
    EPI_ONE(A0, 0, 0, p00) EPI_ONE(A0, 0, 1, p01) EPI_ONE(A0, 0, 2, p02) EPI_ONE(A0, 0, 3, p03) \
    EPI_ONE(A1, 1, 0, p10) EPI_ONE(A1, 1, 1, p11) EPI_ONE(A1, 1, 2, p12) EPI_ONE(A1, 1, 3, p13) \
    EPI_ONE(A2, 2, 0, p20) EPI_ONE(A2, 2, 1, p21) EPI_ONE(A2, 2, 2, p22) EPI_ONE(A2, 2, 3, p23) \
    EPI_ONE(A3, 3, 0, p30) EPI_ONE(A3, 3, 1, p31) EPI_ONE(A3, 3, 2, p32) EPI_ONE(A3, 3, 3, p33) }

  EPI_HH(0, a00, a10, a20, a30)
  EPI_HH(1, a01, a11, a21, a31)
  EPI_HH(2, a02, a12, a22, a32)
  EPI_HH(3, a03, a13, a23, a33)

#define REDW(P, jj, r) { \
    float v = P; \
    v += __shfl_xor(v, 1); v += __shfl_xor(v, 2); \
    v += __shfl_xor(v, 4); v += __shfl_xor(v, 8); \
    if (cc == 0) sc_s[hg][wj * 64 + jj * 16 + q * 4 + r] = v; }

  REDW(p00, 0, 0) REDW(p01, 0, 1) REDW(p02, 0, 2) REDW(p03, 0, 3)
  REDW(p10, 1, 0) REDW(p11, 1, 1) REDW(p12, 1, 2) REDW(p13, 1, 3)
  REDW(p20, 2, 0) REDW(p21, 2, 1) REDW(p22, 2, 2) REDW(p23, 2, 3)
  REDW(p30, 3, 0) REDW(p31, 3, 1) REDW(p32, 3, 2) REDW(p33, 3, 3)
  __syncthreads();

  if (t < 128) {
    float s = sc_s[0][t] + sc_s[1][t] + sc_s[2][t] + sc_s[3][t] + b2[0];
    const int jg = jbase + t;
    if (jg == i) s = NEGV;
    Sc[(size_t)bi * NN + jg] = s;
  }
}

// ---------------- softmax over j, one block per (b,i) --------------------------
__global__ __launch_bounds__(256) void softmax_kernel(const float* __restrict__ Sc,
                                                      float* __restrict__ out) {
  const int bi = blockIdx.x;
  const int t  = threadIdx.x;
  __shared__ float red[NN];
  const float s = Sc[(size_t)bi * NN + t];
  red[t] = s;
  __syncthreads();
  for (int k = 128; k > 0; k >>= 1) {
    if (t < k) red[t] = fmaxf(red[t], red[t + k]);
    __syncthreads();
  }
  const float m = red[0];
  __syncthreads();
  const float e = __expf(s - m);
  red[t] = e;
  __syncthreads();
  for (int k = 128; k > 0; k >>= 1) {
    if (t < k) red[t] += red[t + k];
    __syncthreads();
  }
  out[(size_t)bi * NN + t] = e / red[0];
}

extern "C" void kernel_launch(void* const* d_in, const int* in_sizes, int n_in,
                              void* d_out, int out_size, void* d_ws, size_t ws_size,
                              hipStream_t stream) {
  const float* X  = (const float*)d_in[0];
  const float* W1 = (const float*)d_in[1];
  const float* b1 = (const float*)d_in[2];
  const float* W2 = (const float*)d_in[3];
  const float* b2 = (const float*)d_in[4];
  float* out = (float*)d_out;

  float*     Sws = (float*)d_ws;                             // 1 MB
  float*     Tws = Sws + (size_t)BB * NN * HH;               // 1 MB
  _Float16*  Wst = (_Float16*)(Tws + (size_t)BB * NN * HH);  // 256 KB
  float*     Xtw = (float*)(Wst + (size_t)16 * HH * 32);     // 1 MB
  float*     Scw = Xtw + (size_t)BB * DD * NN;               // 1 MB

  prep_kernel<<<256, 256, 0, stream>>>(X, W1, Sws, Tws, Wst, Xtw);
  score_mfma<<<BB * NN * 2, 512, 0, stream>>>(X, b1, W2, b2, Sws, Tws, Wst, Xtw, Scw);
  softmax_kernel<<<BB * NN, 256, 0, stream>>>(Scw, out);
}